// Round 5
// baseline (211.068 us; speedup 1.0000x reference)
//
#include <hip/hip_runtime.h>
#include <cstddef>

#define B_ 4
#define C_ 512
#define L_ 2048

typedef __attribute__((ext_vector_type(8))) short  short8;   // 8 bf16 (4 VGPRs)
typedef __attribute__((ext_vector_type(4))) float  f32x4;
typedef __attribute__((ext_vector_type(4))) unsigned short us4;

#define AS1 __attribute__((address_space(1)))
#define AS3 __attribute__((address_space(3)))

__device__ __forceinline__ float clip10(float v){ return fminf(fmaxf(v,-10.0f),10.0f); }

// round-to-nearest-even fp32 -> bf16 (finite inputs only; ours are clipped)
__device__ __forceinline__ unsigned short f2bf(float f){
  union { float f; unsigned u; } v; v.f = f;
  unsigned r = v.u + 0x7fffu + ((v.u >> 16) & 1u);
  return (unsigned short)(r >> 16);
}
__device__ __forceinline__ unsigned pk(float lo, float hi){
  return (unsigned)f2bf(lo) | ((unsigned)f2bf(hi) << 16);
}
// async 16B global -> LDS (direct-to-shared DMA)
__device__ __forceinline__ void gl16(const void* g, void* l){
  __builtin_amdgcn_global_load_lds((const AS1 unsigned*)g, (AS3 unsigned*)l, 16, 0, 0);
}

// ---------------------------------------------------------------------------
// Prep (merged): blocks 0..4095 transpose x -> xT bf16; 4096..5119 convert W.
// ---------------------------------------------------------------------------
__global__ __launch_bounds__(256) void prep_k(
    const float* __restrict__ x, const float* __restrict__ Wq,
    const float* __restrict__ Wp, unsigned short* __restrict__ xT,
    unsigned short* __restrict__ Wqb, unsigned short* __restrict__ Wpb)
{
  const int blk = blockIdx.x;
  const int t = threadIdx.x;
  if (blk < 4096){
    __shared__ float tile[32][33];
    const int b = blk>>10, rem = blk&1023;
    const int c0 = (rem>>6)*32, l0 = (rem&63)*32;
    const int cr = t>>3, lc = (t&7)*4;
    const float4 v = *(const float4*)(x + ((size_t)b*C_ + c0+cr)*L_ + l0 + lc);
    tile[cr][lc]=v.x; tile[cr][lc+1]=v.y; tile[cr][lc+2]=v.z; tile[cr][lc+3]=v.w;
    __syncthreads();
    const int lr = t>>3, cc = (t&7)*4;
    const us4 o = { f2bf(tile[cc][lr]), f2bf(tile[cc+1][lr]),
                    f2bf(tile[cc+2][lr]), f2bf(tile[cc+3][lr]) };
    *(us4*)(xT + ((size_t)b*L_ + l0+lr)*C_ + c0 + cc) = o;
  } else {
    const int i = (blk-4096)*256 + t;       // float4 index
    const int NQ = 1536*512/4;
    const float* src; unsigned short* dst; int j;
    if (i < NQ){ src = Wq; dst = Wqb; j = i; }
    else       { src = Wp; dst = Wpb; j = i - NQ; }
    const float4 v = *(const float4*)(src + (size_t)j*4);
    const us4 o = { f2bf(v.x), f2bf(v.y), f2bf(v.z), f2bf(v.w) };
    *(us4*)(dst + (size_t)j*4) = o;
  }
}

// ---------------------------------------------------------------------------
// bf16 MFMA GEMM, 128x128 tile, BK=64, K=512. A=W[m][k], B=Bin[b][n][k].
// LDS chunks XOR-swizzled: physical chunk = logical ^ (row&7).
// MODE 0 (QKV): +bias, clip, q/k stored transposed bf16 [b][l][512],
//               v stored natural bf16 [b][512][l].
// MODE 1 (proj): +bias, fp32 natural [b][512][l].
// ---------------------------------------------------------------------------
template<int MODE>
__global__ __launch_bounds__(256) void mfma_gemm(
    const unsigned short* __restrict__ Wb, const unsigned short* __restrict__ Bin,
    const float* __restrict__ bias,
    unsigned short* __restrict__ qT, unsigned short* __restrict__ kT,
    unsigned short* __restrict__ vN, float* __restrict__ yout)
{
  __shared__ unsigned short SA[128*64];   // [m][k'] bf16, 16KB
  __shared__ unsigned short SB[128*64];   // [n][k'] bf16, 16KB
  const int t = threadIdx.x;
  const int b = blockIdx.z;
  const int mb = blockIdx.y, n0 = blockIdx.x*128, m0 = mb*128;
  const int lane = t&63, w = t>>6, wm = w>>1, wn = w&1;
  const int n = lane&15, q4 = lane>>4;

  f32x4 acc[4][4];
#pragma unroll
  for (int i=0;i<4;i++)
#pragma unroll
    for (int j=0;j<4;j++) acc[i][j] = (f32x4){0.f,0.f,0.f,0.f};

  const unsigned short* Arow = Wb + (size_t)m0*512;
  const unsigned short* Brow = Bin + ((size_t)b*L_ + n0)*512;

  for (int kt=0; kt<8; kt++){
    const int k0 = kt*64;
    __syncthreads();                     // prev-iter fragment reads done
#pragma unroll
    for (int i=0;i<4;i++){
      const int ch = t + 256*i;          // 0..1023 : row=ch>>3, phys chunk=ch&7
      const int row = ch>>3, lc = (ch&7) ^ (row&7);
      gl16(Arow + (size_t)row*512 + k0 + lc*8, &SA[ch*8]);
      gl16(Brow + (size_t)row*512 + k0 + lc*8, &SB[ch*8]);
    }
    __syncthreads();                     // vmcnt(0) drained by compiler
#pragma unroll
    for (int kk=0;kk<2;kk++){
      short8 aF[4], bF[4];
      const int pc = ((kk*4+q4) ^ (n&7))*8;
#pragma unroll
      for (int mt=0;mt<4;mt++) aF[mt] = *(const short8*)&SA[(wm*64+mt*16+n)*64 + pc];
#pragma unroll
      for (int nt=0;nt<4;nt++) bF[nt] = *(const short8*)&SB[(wn*64+nt*16+n)*64 + pc];
#pragma unroll
      for (int mt=0;mt<4;mt++)
#pragma unroll
        for (int nt=0;nt<4;nt++)
          acc[mt][nt] = __builtin_amdgcn_mfma_f32_16x16x32_bf16(aF[mt], bF[nt], acc[mt][nt], 0,0,0);
    }
  }

  // ---- epilogue: C row = m (quad*4+reg), col = n (lane&15)
#pragma unroll
  for (int mt=0;mt<4;mt++){
    const int obase = m0 + wm*64 + mt*16 + q4*4;
    const float b0=bias[obase], b1=bias[obase+1], b2=bias[obase+2], b3=bias[obase+3];
#pragma unroll
    for (int nt=0;nt<4;nt++){
      const int l = n0 + wn*64 + nt*16 + n;
      float r0=acc[mt][nt][0]+b0, r1=acc[mt][nt][1]+b1,
            r2=acc[mt][nt][2]+b2, r3=acc[mt][nt][3]+b3;
      if (MODE==0){
        r0=clip10(r0); r1=clip10(r1); r2=clip10(r2); r3=clip10(r3);
        const int typ = mb>>2;                     // 0=q 1=k 2=v
        const int oin = obase - typ*512;
        if (typ < 2){
          unsigned short* dst = (typ==0) ? qT : kT;
          const us4 o = { f2bf(r0), f2bf(r1), f2bf(r2), f2bf(r3) };
          *(us4*)&dst[((size_t)b*L_ + l)*512 + oin] = o;   // [l][c], 8B store
        } else {
          unsigned short* dst = vN + ((size_t)b*512 + oin)*L_ + l;
          dst[0]=f2bf(r0); dst[(size_t)L_]=f2bf(r1);
          dst[(size_t)2*L_]=f2bf(r2); dst[(size_t)3*L_]=f2bf(r3);
        }
      } else {
        float* dst = yout + ((size_t)b*512 + obase)*L_ + l;
        dst[0]=r0; dst[(size_t)L_]=r1; dst[(size_t)2*L_]=r2; dst[(size_t)3*L_]=r3;
      }
    }
  }
}

// ---------------------------------------------------------------------------
// MFMA attention v3: 256-query i-tile per block (wave = 64 i), grid = 256.
// S^T = K·Q^T (A=K frags from LDS, B=Q frags hoisted from global).
// P^T C-layout -> packed ds_write_b64 (4 consecutive j per lane) -> b128
// A-frag reads. 32-j P window, two halves per iter. K/V double-buffered DMA
// prefetch (issue after barrier, compute on other buffer).
// ---------------------------------------------------------------------------
#define PPW 40   // s_p row pitch in bf16 (32 j + 8 pad; 80 B rows, 16B-aligned)

__global__ __launch_bounds__(256) void attn_v3(
    const unsigned short* __restrict__ qT, const unsigned short* __restrict__ kT,
    const unsigned short* __restrict__ vN, unsigned short* __restrict__ attnT)
{
  __shared__ unsigned short s_p[256*PPW];       // 20 KB, wave-private rows
  __shared__ unsigned short s_kv[2][2][64*64];  // [buf][0=K,1=V], 32 KB
  const int t  = threadIdx.x;
  const int i0 = blockIdx.x*256;
  const int h  = blockIdx.y, b = blockIdx.z;
  const int lane = t&63, w = t>>6, n = lane&15, q4 = lane>>4;

  const unsigned short* kb0 = kT + (size_t)b*L_*512 + h*64;
  const unsigned short* vb  = vN + ((size_t)b*512 + h*64)*L_;

  // ---- Q fragments direct from global (B-operand layout), loop-invariant
  short8 qf[4][2];
#pragma unroll
  for (int it=0; it<4; it++)
#pragma unroll
    for (int kk=0; kk<2; kk++)
      qf[it][kk] = *(const short8*)(qT + ((size_t)b*L_ + i0 + w*64 + it*16 + n)*512
                                       + h*64 + kk*32 + q4*8);

  // ---- prologue DMA: K/V tile 0 into buf 0
#pragma unroll
  for (int i=0;i<2;i++){
    const int ch = t + 256*i, row = ch>>3, lc = (ch&7)^(row&7);
    gl16(kb0 + (size_t)row*512 + lc*8, &s_kv[0][0][ch*8]);
    gl16(vb  + (size_t)row*L_  + lc*8, &s_kv[0][1][ch*8]);
  }

  f32x4 oacc[4][4];
  float dacc[4];
#pragma unroll
  for (int it=0;it<4;it++){ dacc[it]=0.f;
#pragma unroll
    for (int dt=0;dt<4;dt++) oacc[it][dt]=(f32x4){0.f,0.f,0.f,0.f}; }

  const float SCL = 0.125f*1.44269504089f;   // log2(e)/8
  const float LIM = 14.4269504089f;          // 10*log2(e)
  const int   xkey = n & 6;                  // even P-granule swizzle key

  int p = 0;
  for (int j0=0; j0<L_; j0+=64, p^=1){
    __syncthreads();      // buf[p] DMA complete; prior reads of buf[p^1] done
    if (j0+64 < L_){      // prefetch next tile into the other buffer
#pragma unroll
      for (int i=0;i<2;i++){
        const int ch = t + 256*i, row = ch>>3, lc = (ch&7)^(row&7);
        gl16(kb0 + (size_t)(j0+64+row)*512 + lc*8,   &s_kv[p^1][0][ch*8]);
        gl16(vb  + (size_t)row*L_ + (j0+64) + lc*8,  &s_kv[p^1][1][ch*8]);
      }
    }
    const unsigned short* sk = s_kv[p][0];
    const unsigned short* sv = s_kv[p][1];

    // ---- S^T = K·Q^T : D[j][i], A=K[j][d], B=Q[i][d]
    f32x4 sacc[4][4];   // [it][jt]
#pragma unroll
    for (int it=0;it<4;it++)
#pragma unroll
      for (int jt=0;jt<4;jt++) sacc[it][jt]=(f32x4){0.f,0.f,0.f,0.f};
#pragma unroll
    for (int kk=0;kk<2;kk++){
      const int pc = ((kk*4+q4) ^ (n&7))*8;
      short8 aK[4];
#pragma unroll
      for (int jt=0;jt<4;jt++) aK[jt] = *(const short8*)&sk[(jt*16+n)*64 + pc];
#pragma unroll
      for (int it=0;it<4;it++)
#pragma unroll
        for (int jt=0;jt<4;jt++)
          sacc[it][jt] = __builtin_amdgcn_mfma_f32_16x16x32_bf16(aK[jt], qf[it][kk], sacc[it][jt], 0,0,0);
    }

    // ---- two 32-j halves: exp+pack+P-write, then PV on that half
#pragma unroll
    for (int half=0; half<2; half++){
#pragma unroll
      for (int it=0;it<4;it++)
#pragma unroll
        for (int jl=0;jl<2;jl++){
          const int jt = half*2 + jl;
          const float e0 = __builtin_amdgcn_exp2f(__builtin_amdgcn_fmed3f(sacc[it][jt][0]*SCL,-LIM,LIM));
          const float e1 = __builtin_amdgcn_exp2f(__builtin_amdgcn_fmed3f(sacc[it][jt][1]*SCL,-LIM,LIM));
          const float e2 = __builtin_amdgcn_exp2f(__builtin_amdgcn_fmed3f(sacc[it][jt][2]*SCL,-LIM,LIM));
          const float e3 = __builtin_amdgcn_exp2f(__builtin_amdgcn_fmed3f(sacc[it][jt][3]*SCL,-LIM,LIM));
          dacc[it] += (e0+e1)+(e2+e3);
          const unsigned long long pv =
              (unsigned long long)pk(e0,e1) | ((unsigned long long)pk(e2,e3)<<32);
          const int g = (jl*4 + q4) ^ xkey;              // phys granule
          *(unsigned long long*)&s_p[(w*64 + it*16 + n)*PPW + g*4] = pv;
        }
      // PV for this half: A = P[i][j_half], B = V[d][j_half]
      const int pcv = ((half*4+q4) ^ (n&7))*8;
      short8 bV[4];
#pragma unroll
      for (int dt=0;dt<4;dt++) bV[dt] = *(const short8*)&sv[(dt*16+n)*64 + pcv];
      const int gr = (2*q4) ^ xkey;                       // even -> aligned pair
#pragma unroll
      for (int it=0;it<4;it++){
        const short8 pA = *(const short8*)&s_p[(w*64 + it*16 + n)*PPW + gr*4];
#pragma unroll
        for (int dt=0;dt<4;dt++)
          oacc[it][dt] = __builtin_amdgcn_mfma_f32_16x16x32_bf16(pA, bV[dt], oacc[it][dt], 0,0,0);
      }
    }
  }

  // ---- denominators: dacc[it] holds this quad's j-partial for i=it*16+n
  float inv[4];
#pragma unroll
  for (int it=0;it<4;it++){
    float d = dacc[it];
    d += __shfl_xor(d, 16);
    d += __shfl_xor(d, 32);
    inv[it] = 1.0f/d;
  }
  // redistribute: store rows are i = it*16 + q4*4 + r -> fetch inv from lane q4*4+r
  float invr[4][4];
#pragma unroll
  for (int it=0;it<4;it++)
#pragma unroll
    for (int r=0;r<4;r++)
      invr[it][r] = __shfl(inv[it], q4*4 + r);

  // ---- store bf16 [b][l][c]: l = i0+w*64+it*16+q4*4+r, c = h*64+dt*16+n
#pragma unroll
  for (int it=0;it<4;it++)
#pragma unroll
    for (int dt=0;dt<4;dt++)
#pragma unroll
      for (int r=0;r<4;r++){
        const size_t off = ((size_t)b*L_ + i0 + w*64 + it*16 + q4*4 + r)*512 + h*64 + dt*16 + n;
        attnT[off] = f2bf(oacc[it][dt][r]*invr[it][r]);
      }
}

// ---------------------------------------------------------------------------
// GroupNorm split: stats (512 blocks, quarter-group each) + apply.
// Group = 16 ch x 2048 L of (y + x). part[blk] = {sum, sumsq}.
// ---------------------------------------------------------------------------
__global__ __launch_bounds__(256) void gn_stats(
    const float* __restrict__ y, const float* __restrict__ x,
    float* __restrict__ part)
{
  const int blk = blockIdx.x;               // (b<<7)|(g<<2)|s
  const int b = blk>>7, g = (blk>>2)&31, s = blk&3;
  const size_t base = ((size_t)b*C_ + g*16)*L_ + s*512;
  const int t = threadIdx.x;
  float sum=0.f, sq=0.f;
#pragma unroll
  for (int i=0;i<8;i++){
    const int e = i*256 + t;                // 16 rows x 128 float4
    const size_t off = base + (size_t)(e>>7)*L_ + (e&127)*4;
    const float4 vy=*(const float4*)(y+off);
    const float4 vx=*(const float4*)(x+off);
    const float a=vy.x+vx.x, c=vy.y+vx.y, d=vy.z+vx.z, f=vy.w+vx.w;
    sum += (a+c)+(d+f);
    sq  += (a*a+c*c)+(d*d+f*f);
  }
  for (int off=32;off>0;off>>=1){
    sum += __shfl_down(sum,off);
    sq  += __shfl_down(sq,off);
  }
  __shared__ float red[8];
  if ((t&63)==0){ red[(t>>6)*2]=sum; red[(t>>6)*2+1]=sq; }
  __syncthreads();
  if (t==0){
    part[blk*2+0] = red[0]+red[2]+red[4]+red[6];
    part[blk*2+1] = red[1]+red[3]+red[5]+red[7];
  }
}

__global__ __launch_bounds__(256) void gn_apply(
    const float* __restrict__ y, const float* __restrict__ x,
    const float* __restrict__ part,
    const float* __restrict__ gamma, const float* __restrict__ beta,
    float* __restrict__ out)
{
  const int blk = blockIdx.x;
  const int b = blk>>7, g = (blk>>2)&31, s = blk&3;
  const int bg8 = (blk & ~3)*2;
  const float sum = (part[bg8+0]+part[bg8+2])+(part[bg8+4]+part[bg8+6]);
  const float sq  = (part[bg8+1]+part[bg8+3])+(part[bg8+5]+part[bg8+7]);
  const float mu = sum*(1.0f/32768.0f);
  const float rs = rsqrtf(sq*(1.0f/32768.0f) - mu*mu + 1e-5f);
  const size_t base = ((size_t)b*C_ + g*16)*L_ + s*512;
  const int t = threadIdx.x;
#pragma unroll
  for (int i=0;i<8;i++){
    const int e = i*256 + t;
    const int row = e>>7;
    const size_t off = base + (size_t)row*L_ + (e&127)*4;
    const int c = g*16 + row;
    const float ga = gamma[c], be = beta[c];
    const float4 vy=*(const float4*)(y+off);
    const float4 vx=*(const float4*)(x+off);
    float4 r;
    r.x=((vy.x+vx.x)-mu)*rs*ga+be;
    r.y=((vy.y+vx.y)-mu)*rs*ga+be;
    r.z=((vy.z+vx.z)-mu)*rs*ga+be;
    r.w=((vy.w+vx.w)-mu)*rs*ga+be;
    *(float4*)(out+off)=r;
  }
}

// ---------------------------------------------------------------------------
extern "C" void kernel_launch(void* const* d_in, const int* in_sizes, int n_in,
                              void* d_out, int out_size, void* d_ws, size_t ws_size,
                              hipStream_t stream)
{
  (void)in_sizes; (void)n_in; (void)out_size; (void)ws_size;
  const float* x     = (const float*)d_in[0];
  const float* Wqkv  = (const float*)d_in[1];
  const float* bqkv  = (const float*)d_in[2];
  const float* Wproj = (const float*)d_in[3];
  const float* bproj = (const float*)d_in[4];
  const float* gamma = (const float*)d_in[5];
  const float* beta  = (const float*)d_in[6];
  float* out = (float*)d_out;
  char* ws = (char*)d_ws;

  const size_t MB = 1024*1024;
  unsigned short* qT    = (unsigned short*)(ws);            //  8 MB [b][l][512]
  unsigned short* kT    = (unsigned short*)(ws +  8*MB);    //  8 MB [b][l][512]
  unsigned short* vN    = (unsigned short*)(ws + 16*MB);    //  8 MB [b][512][l]
  unsigned short* attnT = (unsigned short*)(ws + 24*MB);    //  8 MB [b][l][512]
  unsigned short* xT    = (unsigned short*)(ws + 32*MB);    //  8 MB [b][l][512]
  unsigned short* Wqb   = (unsigned short*)(ws + 40*MB);    // 1.5 MB
  unsigned short* Wpb   = (unsigned short*)(ws + 42*MB);    // 0.5 MB
  float*          y     = (float*)        (ws + 43*MB);     // 16 MB [b][512][l]
  float*          part  = (float*)        (ws + 59*MB);     // 4 KB

  prep_k      <<<dim3(5120),   256,0,stream>>>(x, Wqkv, Wproj, xT, Wqb, Wpb);
  mfma_gemm<0><<<dim3(16,12,4),256,0,stream>>>(Wqb, xT,    bqkv , qT,kT,vN, nullptr);
  attn_v3     <<<dim3(8, 8, 4),256,0,stream>>>(qT, kT, vN, attnT);
  mfma_gemm<1><<<dim3(16, 4,4),256,0,stream>>>(Wpb, attnT, bproj, nullptr,nullptr,nullptr, y);
  gn_stats    <<<dim3(512),    256,0,stream>>>(y, x, part);
  gn_apply    <<<dim3(512),    256,0,stream>>>(y, x, part, gamma, beta, out);
}

// Round 6
// 201.295 us; speedup vs baseline: 1.0485x; 1.0485x over previous
//
#include <hip/hip_runtime.h>
#include <cstddef>

#define B_ 4
#define C_ 512
#define L_ 2048

typedef __attribute__((ext_vector_type(8))) short  short8;   // 8 bf16 (4 VGPRs)
typedef __attribute__((ext_vector_type(4))) float  f32x4;
typedef __attribute__((ext_vector_type(4))) unsigned short us4;

#define AS1 __attribute__((address_space(1)))
#define AS3 __attribute__((address_space(3)))

__device__ __forceinline__ float clip10(float v){ return fminf(fmaxf(v,-10.0f),10.0f); }

// round-to-nearest-even fp32 -> bf16 (finite inputs only; ours are clipped)
__device__ __forceinline__ unsigned short f2bf(float f){
  union { float f; unsigned u; } v; v.f = f;
  unsigned r = v.u + 0x7fffu + ((v.u >> 16) & 1u);
  return (unsigned short)(r >> 16);
}
__device__ __forceinline__ unsigned pk(float lo, float hi){
  return (unsigned)f2bf(lo) | ((unsigned)f2bf(hi) << 16);
}
// async 16B global -> LDS (direct-to-shared DMA)
__device__ __forceinline__ void gl16(const void* g, void* l){
  __builtin_amdgcn_global_load_lds((const AS1 unsigned*)g, (AS3 unsigned*)l, 16, 0, 0);
}

// ---------------------------------------------------------------------------
// Prep (merged): blocks 0..4095 transpose x -> xT bf16; 4096..5119 convert W.
// ---------------------------------------------------------------------------
__global__ __launch_bounds__(256) void prep_k(
    const float* __restrict__ x, const float* __restrict__ Wq,
    const float* __restrict__ Wp, unsigned short* __restrict__ xT,
    unsigned short* __restrict__ Wqb, unsigned short* __restrict__ Wpb)
{
  const int blk = blockIdx.x;
  const int t = threadIdx.x;
  if (blk < 4096){
    __shared__ float tile[32][33];
    const int b = blk>>10, rem = blk&1023;
    const int c0 = (rem>>6)*32, l0 = (rem&63)*32;
    const int cr = t>>3, lc = (t&7)*4;
    const float4 v = *(const float4*)(x + ((size_t)b*C_ + c0+cr)*L_ + l0 + lc);
    tile[cr][lc]=v.x; tile[cr][lc+1]=v.y; tile[cr][lc+2]=v.z; tile[cr][lc+3]=v.w;
    __syncthreads();
    const int lr = t>>3, cc = (t&7)*4;
    const us4 o = { f2bf(tile[cc][lr]), f2bf(tile[cc+1][lr]),
                    f2bf(tile[cc+2][lr]), f2bf(tile[cc+3][lr]) };
    *(us4*)(xT + ((size_t)b*L_ + l0+lr)*C_ + c0 + cc) = o;
  } else {
    const int i = (blk-4096)*256 + t;       // float4 index
    const int NQ = 1536*512/4;
    const float* src; unsigned short* dst; int j;
    if (i < NQ){ src = Wq; dst = Wqb; j = i; }
    else       { src = Wp; dst = Wpb; j = i - NQ; }
    const float4 v = *(const float4*)(src + (size_t)j*4);
    const us4 o = { f2bf(v.x), f2bf(v.y), f2bf(v.z), f2bf(v.w) };
    *(us4*)(dst + (size_t)j*4) = o;
  }
}

// ---------------------------------------------------------------------------
// bf16 MFMA GEMM, 128x128 tile, BK=64, K=512. A=W[m][k], B=Bin[b][n][k].
// LDS chunks XOR-swizzled: physical chunk = logical ^ (row&7).
// MODE 0 (QKV): +bias, clip, q/k stored transposed bf16 [b][l][512],
//               v stored natural bf16 [b][512][l].
// MODE 1 (proj): +bias, fp32 natural [b][512][l].
// ---------------------------------------------------------------------------
template<int MODE>
__global__ __launch_bounds__(256) void mfma_gemm(
    const unsigned short* __restrict__ Wb, const unsigned short* __restrict__ Bin,
    const float* __restrict__ bias,
    unsigned short* __restrict__ qT, unsigned short* __restrict__ kT,
    unsigned short* __restrict__ vN, float* __restrict__ yout)
{
  __shared__ unsigned short SA[128*64];   // [m][k'] bf16, 16KB
  __shared__ unsigned short SB[128*64];   // [n][k'] bf16, 16KB
  const int t = threadIdx.x;
  const int b = blockIdx.z;
  const int mb = blockIdx.y, n0 = blockIdx.x*128, m0 = mb*128;
  const int lane = t&63, w = t>>6, wm = w>>1, wn = w&1;
  const int n = lane&15, q4 = lane>>4;

  f32x4 acc[4][4];
#pragma unroll
  for (int i=0;i<4;i++)
#pragma unroll
    for (int j=0;j<4;j++) acc[i][j] = (f32x4){0.f,0.f,0.f,0.f};

  const unsigned short* Arow = Wb + (size_t)m0*512;
  const unsigned short* Brow = Bin + ((size_t)b*L_ + n0)*512;

  for (int kt=0; kt<8; kt++){
    const int k0 = kt*64;
    __syncthreads();                     // prev-iter fragment reads done
#pragma unroll
    for (int i=0;i<4;i++){
      const int ch = t + 256*i;          // 0..1023 : row=ch>>3, phys chunk=ch&7
      const int row = ch>>3, lc = (ch&7) ^ (row&7);
      gl16(Arow + (size_t)row*512 + k0 + lc*8, &SA[ch*8]);
      gl16(Brow + (size_t)row*512 + k0 + lc*8, &SB[ch*8]);
    }
    __syncthreads();                     // vmcnt(0) drained by compiler
#pragma unroll
    for (int kk=0;kk<2;kk++){
      short8 aF[4], bF[4];
      const int pc = ((kk*4+q4) ^ (n&7))*8;
#pragma unroll
      for (int mt=0;mt<4;mt++) aF[mt] = *(const short8*)&SA[(wm*64+mt*16+n)*64 + pc];
#pragma unroll
      for (int nt=0;nt<4;nt++) bF[nt] = *(const short8*)&SB[(wn*64+nt*16+n)*64 + pc];
#pragma unroll
      for (int mt=0;mt<4;mt++)
#pragma unroll
        for (int nt=0;nt<4;nt++)
          acc[mt][nt] = __builtin_amdgcn_mfma_f32_16x16x32_bf16(aF[mt], bF[nt], acc[mt][nt], 0,0,0);
    }
  }

  // ---- epilogue: C row = m (quad*4+reg), col = n (lane&15)
#pragma unroll
  for (int mt=0;mt<4;mt++){
    const int obase = m0 + wm*64 + mt*16 + q4*4;
    const float b0=bias[obase], b1=bias[obase+1], b2=bias[obase+2], b3=bias[obase+3];
#pragma unroll
    for (int nt=0;nt<4;nt++){
      const int l = n0 + wn*64 + nt*16 + n;
      float r0=acc[mt][nt][0]+b0, r1=acc[mt][nt][1]+b1,
            r2=acc[mt][nt][2]+b2, r3=acc[mt][nt][3]+b3;
      if (MODE==0){
        r0=clip10(r0); r1=clip10(r1); r2=clip10(r2); r3=clip10(r3);
        const int typ = mb>>2;                     // 0=q 1=k 2=v
        const int oin = obase - typ*512;
        if (typ < 2){
          unsigned short* dst = (typ==0) ? qT : kT;
          const us4 o = { f2bf(r0), f2bf(r1), f2bf(r2), f2bf(r3) };
          *(us4*)&dst[((size_t)b*L_ + l)*512 + oin] = o;   // [l][c], 8B store
        } else {
          unsigned short* dst = vN + ((size_t)b*512 + oin)*L_ + l;
          dst[0]=f2bf(r0); dst[(size_t)L_]=f2bf(r1);
          dst[(size_t)2*L_]=f2bf(r2); dst[(size_t)3*L_]=f2bf(r3);
        }
      } else {
        float* dst = yout + ((size_t)b*512 + obase)*L_ + l;
        dst[0]=r0; dst[(size_t)L_]=r1; dst[(size_t)2*L_]=r2; dst[(size_t)3*L_]=r3;
      }
    }
  }
}

// ---------------------------------------------------------------------------
// MFMA attention v4 = v2 shape (128-i tile, wave = 32 i, grid 512) +
//  (a) S^T formulation: mfma(K,Q) -> lane=i col, quad*4+reg = 4 consecutive j
//      -> exp pack -> 8 ds_write_b64 per wave-iter; P pitch 72 (2-way only).
//  (b) K/V double-buffered DMA, ONE barrier per iter, prefetch after barrier.
//  (c) Q fragments loaded once directly from global (no Q LDS, no extra bar).
// ---------------------------------------------------------------------------
#define PP 72   // s_p pitch in bf16: 144B rows, 16B-aligned, 2-way banks max

__global__ __launch_bounds__(256) void attn_v4(
    const unsigned short* __restrict__ qT, const unsigned short* __restrict__ kT,
    const unsigned short* __restrict__ vN, unsigned short* __restrict__ attnT)
{
  __shared__ unsigned short s_p[128*PP];        // 18 KB, wave-private rows
  __shared__ unsigned short s_kv[2][2][64*64];  // [buf][0=K,1=V], 32 KB
  const int t  = threadIdx.x;
  const int i0 = blockIdx.x*128;
  const int h  = blockIdx.y, b = blockIdx.z;
  const int lane = t&63, w = t>>6, n = lane&15, q4 = lane>>4;

  const unsigned short* kb0 = kT + (size_t)b*L_*512 + h*64;
  const unsigned short* vb  = vN + ((size_t)b*512 + h*64)*L_;

  // ---- Q fragments direct from global (rows i, k=d), loop-invariant
  short8 qf[2][2];
#pragma unroll
  for (int mt=0; mt<2; mt++)
#pragma unroll
    for (int kk=0; kk<2; kk++)
      qf[mt][kk] = *(const short8*)(qT + ((size_t)b*L_ + i0 + w*32 + mt*16 + n)*512
                                       + h*64 + kk*32 + q4*8);

  // ---- prologue DMA: K/V tile 0 into buf 0
#pragma unroll
  for (int i=0;i<2;i++){
    const int ch = t + 256*i, row = ch>>3, lc = (ch&7)^(row&7);
    gl16(kb0 + (size_t)row*512 + lc*8, &s_kv[0][0][ch*8]);
    gl16(vb  + (size_t)row*L_  + lc*8, &s_kv[0][1][ch*8]);
  }

  f32x4 oacc[2][4];
  float dacc[2];
#pragma unroll
  for (int mt=0;mt<2;mt++){ dacc[mt]=0.f;
#pragma unroll
    for (int dt=0;dt<4;dt++) oacc[mt][dt]=(f32x4){0.f,0.f,0.f,0.f}; }

  const float SCL = 0.125f*1.44269504089f;   // log2(e)/8
  const float LIM = 14.4269504089f;          // 10*log2(e)

  int p = 0;
  for (int j0=0; j0<L_; j0+=64, p^=1){
    __syncthreads();      // buf[p] DMA drained; all reads of buf[p] (prev use) done
    if (j0+64 < L_){      // prefetch next tile; stays in flight through compute
#pragma unroll
      for (int i=0;i<2;i++){
        const int ch = t + 256*i, row = ch>>3, lc = (ch&7)^(row&7);
        gl16(kb0 + (size_t)(j0+64+row)*512 + lc*8,  &s_kv[p^1][0][ch*8]);
        gl16(vb  + (size_t)row*L_ + (j0+64) + lc*8, &s_kv[p^1][1][ch*8]);
      }
    }
    const unsigned short* sk = s_kv[p][0];
    const unsigned short* sv = s_kv[p][1];

    // ---- S^T = K·Q^T : D[j][i]; lane col = i (n), rows = j (q4*4+r)
    f32x4 sacc[2][4];   // [mt][jt]
#pragma unroll
    for (int mt=0;mt<2;mt++)
#pragma unroll
      for (int jt=0;jt<4;jt++) sacc[mt][jt]=(f32x4){0.f,0.f,0.f,0.f};
#pragma unroll
    for (int kk=0;kk<2;kk++){
      const int pc = ((kk*4+q4) ^ (n&7))*8;
      short8 aK[4];
#pragma unroll
      for (int jt=0;jt<4;jt++) aK[jt] = *(const short8*)&sk[(jt*16+n)*64 + pc];
#pragma unroll
      for (int mt=0;mt<2;mt++)
#pragma unroll
        for (int jt=0;jt<4;jt++)
          sacc[mt][jt] = __builtin_amdgcn_mfma_f32_16x16x32_bf16(aK[jt], qf[mt][kk], sacc[mt][jt], 0,0,0);
    }

    // ---- exp + pack 4 consecutive j -> one b64 per (mt,jt); row = own i
#pragma unroll
    for (int mt=0;mt<2;mt++)
#pragma unroll
      for (int jt=0;jt<4;jt++){
        const float e0 = __builtin_amdgcn_exp2f(__builtin_amdgcn_fmed3f(sacc[mt][jt][0]*SCL,-LIM,LIM));
        const float e1 = __builtin_amdgcn_exp2f(__builtin_amdgcn_fmed3f(sacc[mt][jt][1]*SCL,-LIM,LIM));
        const float e2 = __builtin_amdgcn_exp2f(__builtin_amdgcn_fmed3f(sacc[mt][jt][2]*SCL,-LIM,LIM));
        const float e3 = __builtin_amdgcn_exp2f(__builtin_amdgcn_fmed3f(sacc[mt][jt][3]*SCL,-LIM,LIM));
        dacc[mt] += (e0+e1)+(e2+e3);
        const unsigned long long pv =
            (unsigned long long)pk(e0,e1) | ((unsigned long long)pk(e2,e3)<<32);
        *(unsigned long long*)&s_p[(w*32 + mt*16 + n)*PP + jt*16 + q4*4] = pv;
      }
    // no barrier: P rows are wave-private (write & read by same wave)

    // ---- O += P·V^T : A = P[i][j] rows, B = V[d][j] rows
#pragma unroll
    for (int kk=0;kk<2;kk++){
      const int pcv = ((kk*4+q4) ^ (n&7))*8;
      short8 bV[4], pA[2];
#pragma unroll
      for (int dt=0;dt<4;dt++) bV[dt] = *(const short8*)&sv[(dt*16+n)*64 + pcv];
#pragma unroll
      for (int mt=0;mt<2;mt++)
        pA[mt] = *(const short8*)&s_p[(w*32 + mt*16 + n)*PP + kk*32 + q4*8];
#pragma unroll
      for (int mt=0;mt<2;mt++)
#pragma unroll
        for (int dt=0;dt<4;dt++)
          oacc[mt][dt] = __builtin_amdgcn_mfma_f32_16x16x32_bf16(pA[mt], bV[dt], oacc[mt][dt], 0,0,0);
    }
  }

  // ---- denominator: dacc[mt] = partial for row i = mt*16+n over this q4's j
  float inv[2];
#pragma unroll
  for (int mt=0;mt<2;mt++){
    float d = dacc[mt];
    d += __shfl_xor(d, 16);
    d += __shfl_xor(d, 32);
    inv[mt] = 1.0f/d;
  }
  // redistribute: output rows are i = mt*16 + q4*4 + r -> inv lives at lane q4*4+r
  float invr[2][4];
#pragma unroll
  for (int mt=0;mt<2;mt++)
#pragma unroll
    for (int r=0;r<4;r++)
      invr[mt][r] = __shfl(inv[mt], q4*4 + r);

  // ---- store bf16 [b][l][c]: l = i0+w*32+mt*16+q4*4+r, c = h*64+dt*16+n
#pragma unroll
  for (int mt=0;mt<2;mt++)
#pragma unroll
    for (int dt=0;dt<4;dt++)
#pragma unroll
      for (int r=0;r<4;r++){
        const size_t off = ((size_t)b*L_ + i0 + w*32 + mt*16 + q4*4 + r)*512 + h*64 + dt*16 + n;
        attnT[off] = f2bf(oacc[mt][dt][r]*invr[mt][r]);
      }
}

// ---------------------------------------------------------------------------
// GroupNorm split: stats (512 blocks, quarter-group each) + apply.
// Group = 16 ch x 2048 L of (y + x). part[blk] = {sum, sumsq}.
// ---------------------------------------------------------------------------
__global__ __launch_bounds__(256) void gn_stats(
    const float* __restrict__ y, const float* __restrict__ x,
    float* __restrict__ part)
{
  const int blk = blockIdx.x;               // (b<<7)|(g<<2)|s
  const int b = blk>>7, g = (blk>>2)&31, s = blk&3;
  const size_t base = ((size_t)b*C_ + g*16)*L_ + s*512;
  const int t = threadIdx.x;
  float sum=0.f, sq=0.f;
#pragma unroll
  for (int i=0;i<8;i++){
    const int e = i*256 + t;                // 16 rows x 128 float4
    const size_t off = base + (size_t)(e>>7)*L_ + (e&127)*4;
    const float4 vy=*(const float4*)(y+off);
    const float4 vx=*(const float4*)(x+off);
    const float a=vy.x+vx.x, c=vy.y+vx.y, d=vy.z+vx.z, f=vy.w+vx.w;
    sum += (a+c)+(d+f);
    sq  += (a*a+c*c)+(d*d+f*f);
  }
  for (int off=32;off>0;off>>=1){
    sum += __shfl_down(sum,off);
    sq  += __shfl_down(sq,off);
  }
  __shared__ float red[8];
  if ((t&63)==0){ red[(t>>6)*2]=sum; red[(t>>6)*2+1]=sq; }
  __syncthreads();
  if (t==0){
    part[blk*2+0] = red[0]+red[2]+red[4]+red[6];
    part[blk*2+1] = red[1]+red[3]+red[5]+red[7];
  }
}

__global__ __launch_bounds__(256) void gn_apply(
    const float* __restrict__ y, const float* __restrict__ x,
    const float* __restrict__ part,
    const float* __restrict__ gamma, const float* __restrict__ beta,
    float* __restrict__ out)
{
  const int blk = blockIdx.x;
  const int b = blk>>7, g = (blk>>2)&31, s = blk&3;
  const int bg8 = (blk & ~3)*2;
  const float sum = (part[bg8+0]+part[bg8+2])+(part[bg8+4]+part[bg8+6]);
  const float sq  = (part[bg8+1]+part[bg8+3])+(part[bg8+5]+part[bg8+7]);
  const float mu = sum*(1.0f/32768.0f);
  const float rs = rsqrtf(sq*(1.0f/32768.0f) - mu*mu + 1e-5f);
  const size_t base = ((size_t)b*C_ + g*16)*L_ + s*512;
  const int t = threadIdx.x;
#pragma unroll
  for (int i=0;i<8;i++){
    const int e = i*256 + t;
    const int row = e>>7;
    const size_t off = base + (size_t)row*L_ + (e&127)*4;
    const int c = g*16 + row;
    const float ga = gamma[c], be = beta[c];
    const float4 vy=*(const float4*)(y+off);
    const float4 vx=*(const float4*)(x+off);
    float4 r;
    r.x=((vy.x+vx.x)-mu)*rs*ga+be;
    r.y=((vy.y+vx.y)-mu)*rs*ga+be;
    r.z=((vy.z+vx.z)-mu)*rs*ga+be;
    r.w=((vy.w+vx.w)-mu)*rs*ga+be;
    *(float4*)(out+off)=r;
  }
}

// ---------------------------------------------------------------------------
extern "C" void kernel_launch(void* const* d_in, const int* in_sizes, int n_in,
                              void* d_out, int out_size, void* d_ws, size_t ws_size,
                              hipStream_t stream)
{
  (void)in_sizes; (void)n_in; (void)out_size; (void)ws_size;
  const float* x     = (const float*)d_in[0];
  const float* Wqkv  = (const float*)d_in[1];
  const float* bqkv  = (const float*)d_in[2];
  const float* Wproj = (const float*)d_in[3];
  const float* bproj = (const float*)d_in[4];
  const float* gamma = (const float*)d_in[5];
  const float* beta  = (const float*)d_in[6];
  float* out = (float*)d_out;
  char* ws = (char*)d_ws;

  const size_t MB = 1024*1024;
  unsigned short* qT    = (unsigned short*)(ws);            //  8 MB [b][l][512]
  unsigned short* kT    = (unsigned short*)(ws +  8*MB);    //  8 MB [b][l][512]
  unsigned short* vN    = (unsigned short*)(ws + 16*MB);    //  8 MB [b][512][l]
  unsigned short* attnT = (unsigned short*)(ws + 24*MB);    //  8 MB [b][l][512]
  unsigned short* xT    = (unsigned short*)(ws + 32*MB);    //  8 MB [b][l][512]
  unsigned short* Wqb   = (unsigned short*)(ws + 40*MB);    // 1.5 MB
  unsigned short* Wpb   = (unsigned short*)(ws + 42*MB);    // 0.5 MB
  float*          y     = (float*)        (ws + 43*MB);     // 16 MB [b][512][l]
  float*          part  = (float*)        (ws + 59*MB);     // 4 KB

  prep_k      <<<dim3(5120),   256,0,stream>>>(x, Wqkv, Wproj, xT, Wqb, Wpb);
  mfma_gemm<0><<<dim3(16,12,4),256,0,stream>>>(Wqb, xT,    bqkv , qT,kT,vN, nullptr);
  attn_v4     <<<dim3(16,8,4), 256,0,stream>>>(qT, kT, vN, attnT);
  mfma_gemm<1><<<dim3(16, 4,4),256,0,stream>>>(Wpb, attnT, bproj, nullptr,nullptr,nullptr, y);
  gn_stats    <<<dim3(512),    256,0,stream>>>(y, x, part);
  gn_apply    <<<dim3(512),    256,0,stream>>>(y, x, part, gamma, beta, out);
}